// Round 11
// baseline (711.176 us; speedup 1.0000x reference)
//
#include <hip/hip_runtime.h>
#include <math.h>

// clDice loss on MI355X (gfx950).
// soft_skeletonize = 20 iterations of:
//   m = minpool3(x); contour = relu(maxpool3(m) - m); x = relu(x - contour)
// Round-11: cross-round invariant: VALU-issue cyc/wave-iter ~ fixed (~1000)
// regardless of fp32/f16/LDS/DPP -> minimize wave-iter COUNT and stalls:
//  - K=5 fused iters/launch, 4 launches (f16 state ~16 VGPR/stage -> ~100,
//    stays under the 128-VGPR 4-wave/SIMD cliff; R6's K=5 spill was fp32).
//    Wave-iters -11.4%, intermediate traffic -25%, 1 fewer launch.
//  - Edge-exchange LDS split into two stride-4B unsigned arrays (col0-pairs,
//    col3-pairs): kills round-10's 3.67e6 4-way bank conflicts (uint2 .y
//    reads were stride-8B).
//  - Interior fast path: bands 1..30 never see an image edge -> mask-free
//    loop (no load guards / rm / em clamps), block-uniform dispatch.
// Structure otherwise = round-10 (proven absmax 0.0): packed-f16 pipeline,
// both tensors per grid (z=32), 1 barrier/row-iter, per-block partials.

#define IMG_H 1024
#define IMG_W 1024
#define IMG_N (IMG_H * IMG_W)
#define NIMG  16
#define NZ    32                    // 16 pred + 16 gt images
#define BH    32                    // output rows per band
#define NBANDS (IMG_H / BH)         // 32
#define K     5                     // fused skeleton iterations per launch
#define EW    258                   // 256 lanes + 2 guard slots
#define NBLK  (NZ * NBANDS)         // 1024 blocks per launch
#define ITER_PAIRS ((BH + 6 * K) / 2)   // 31 pairs = 62 row-iterations

typedef _Float16 h2 __attribute__((ext_vector_type(2)));

__device__ __forceinline__ h2 hmin2(h2 a, h2 b) { return __builtin_elementwise_min(a, b); }
__device__ __forceinline__ h2 hmax2(h2 a, h2 b) { return __builtin_elementwise_max(a, b); }

union U32H { unsigned u; h2 h; };
__device__ __forceinline__ unsigned as_u(h2 h) { U32H t; t.h = h; return t.u; }
__device__ __forceinline__ h2 as_h2(unsigned u) { U32H t; t.u = u; return t.h; }

#define HINF  ((_Float16)__builtin_huge_valf())
#define PINF2 ((h2){HINF, HINF})
#define NINF2 ((h2){-HINF, -HINF})

struct Hp { h2 lo, hi; };           // 4 image columns per lane
struct St { Hp hm1, hm2, m2, m3, q1, q2, x1, x2, x3, xc; };

// One pipeline stage. Edge arrays (stride 4B, conflict-free):
//   eX[slot] = col0 pair {x,m} of lane slot-1 (read by its LEFT neighbor's
//              right-lookup at slot t+2)
//   eY[slot] = col3 pair {x,m} of lane slot-1 (read by RIGHT neighbor at t)
template<int BUF, bool MASK>
__device__ __forceinline__ Hp stage_step(
    St& s, h2 rmask, int t,
    const unsigned (&eX)[2][EW], const unsigned (&eY)[2][EW])
{
    h2 lp = as_h2(eY[BUF][t]);          // left nbr's col3 {x, m}
    h2 rp = as_h2(eX[BUF][t + 2]);      // right nbr's col0 {x, m}
    // h-min3 of x row
    h2 midx = (h2){s.xc.lo[1], s.xc.hi[0]};
    h2 hlo = hmin2(hmin2((h2){lp[0], s.xc.lo[0]}, s.xc.lo), midx);
    h2 hhi = hmin2(hmin2(midx, s.xc.hi), (h2){s.xc.hi[1], rp[0]});
    // v-min3 (+ row mask only on masked path)
    h2 mlo = hmin2(hmin2(s.hm1.lo, s.hm2.lo), hlo);
    h2 mhi = hmin2(hmin2(s.hm1.hi, s.hm2.hi), hhi);
    if constexpr (MASK) { mlo = hmin2(mlo, rmask); mhi = hmin2(mhi, rmask); }
    // h-max3 of m (previous iter's m, in m2)
    h2 midm = (h2){s.m2.lo[1], s.m2.hi[0]};
    h2 qlo = hmax2(hmax2((h2){lp[1], s.m2.lo[0]}, s.m2.lo), midm);
    h2 qhi = hmax2(hmax2(midm, s.m2.hi), (h2){s.m2.hi[1], rp[1]});
    // v-max3
    h2 Mlo = hmax2(hmax2(s.q1.lo, s.q2.lo), qlo);
    h2 Mhi = hmax2(hmax2(s.q1.hi, s.q2.hi), qhi);
    // contour + relu update
    const h2 Z2 = (h2){(_Float16)0.f, (_Float16)0.f};
    h2 elo = hmax2(s.x3.lo - hmax2(Mlo - s.m3.lo, Z2), Z2);
    h2 ehi = hmax2(s.x3.hi - hmax2(Mhi - s.m3.hi, Z2), Z2);
    // ring shifts
    s.hm1 = s.hm2; s.hm2.lo = hlo; s.hm2.hi = hhi;
    s.m3  = s.m2;  s.m2.lo  = mlo; s.m2.hi  = mhi;
    s.q1  = s.q2;  s.q2.lo  = qlo; s.q2.hi  = qhi;
    s.x3  = s.x2;  s.x2 = s.x1;    s.x1 = s.xc;
    Hp e; e.lo = elo; e.hi = ehi;
    return e;
}

template<int BUF, bool MASK, int FIRST, int LAST>
__device__ __forceinline__ void iter_step(
    int y, int t, int c, int r0, St (&st)[K],
    const float* __restrict__ f32src, const unsigned short* __restrict__ bsrc,
    unsigned short* __restrict__ bdst, const float* __restrict__ oth,
    float& a1, float& a2,
    unsigned (&eX)[K][2][EW], unsigned (&eY)[K][2][EW])
{
    // prefetch stage-0 input row y+1
    Hp xnext;
    if constexpr (MASK) {
        xnext.lo = PINF2; xnext.hi = PINF2;
        if ((unsigned)(y + 1) < (unsigned)IMG_H) {
            if constexpr (FIRST) {
                float4 f = *(const float4*)(f32src + (size_t)(y + 1) * IMG_W + c);
                xnext.lo = (h2){(_Float16)f.x, (_Float16)f.y};
                xnext.hi = (h2){(_Float16)f.z, (_Float16)f.w};
            } else {
                uint2 u = *(const uint2*)(bsrc + (size_t)(y + 1) * IMG_W + c);
                xnext.lo = as_h2(u.x); xnext.hi = as_h2(u.y);
            }
        }
    } else {
        if constexpr (FIRST) {
            float4 f = *(const float4*)(f32src + (size_t)(y + 1) * IMG_W + c);
            xnext.lo = (h2){(_Float16)f.x, (_Float16)f.y};
            xnext.hi = (h2){(_Float16)f.z, (_Float16)f.w};
        } else {
            uint2 u = *(const uint2*)(bsrc + (size_t)(y + 1) * IMG_W + c);
            xnext.lo = as_h2(u.x); xnext.hi = as_h2(u.y);
        }
    }
    __syncthreads();                         // prev-iter edge writes visible

    h2 rm = PINF2;
    if constexpr (MASK)
        rm = ((unsigned)(y - 4 * (K - 1) - 1) < (unsigned)IMG_H) ? PINF2 : NINF2;
    Hp eK = stage_step<BUF, MASK>(st[K - 1], rm, t, eX[K - 1], eY[K - 1]);
    #pragma unroll
    for (int k = K - 2; k >= 0; --k) {
        if constexpr (MASK)
            rm = ((unsigned)(y - 4 * k - 1) < (unsigned)IMG_H) ? PINF2 : NINF2;
        Hp e = stage_step<BUF, MASK>(st[k], rm, t, eX[k], eY[k]);
        if constexpr (MASK) {
            h2 em = ((unsigned)(y - 4 * k - 3) < (unsigned)IMG_H) ? NINF2 : PINF2;
            st[k + 1].xc.lo = hmax2(e.lo, em);
            st[k + 1].xc.hi = hmax2(e.hi, em);
        } else {
            st[k + 1].xc = e;
        }
    }
    st[0].xc = xnext;

    // edge writes for next iteration (new xc + this iter's m, now in m2)
    #pragma unroll
    for (int k = 0; k < K; ++k) {
        eX[k][BUF ^ 1][t + 1] = as_u((h2){st[k].xc.lo[0], st[k].m2.lo[0]});
        eY[k][BUF ^ 1][t + 1] = as_u((h2){st[k].xc.hi[1], st[k].m2.hi[1]});
    }

    int orow = y - (4 * (K - 1) + 3);        // y - 19
    if ((unsigned)(orow - r0) < (unsigned)BH) {
        if constexpr (!LAST) {
            *(uint2*)(bdst + (size_t)orow * IMG_W + c) =
                make_uint2(as_u(eK.lo), as_u(eK.hi));
        } else {
            float4 ov = *(const float4*)(oth + (size_t)orow * IMG_W + c);
            float e0 = (float)eK.lo[0], e1 = (float)eK.lo[1];
            float e2f = (float)eK.hi[0], e3 = (float)eK.hi[1];
            a1 += e0 * ov.x + e1 * ov.y + e2f * ov.z + e3 * ov.w;
            a2 += e0 + e1 + e2f + e3;
        }
    }
}

template<bool MASK, int FIRST, int LAST>
__device__ __forceinline__ void run_band(
    int y0, int t, int c, int r0, St (&st)[K],
    const float* __restrict__ f32src, const unsigned short* __restrict__ bsrc,
    unsigned short* __restrict__ bdst, const float* __restrict__ oth,
    float& a1, float& a2,
    unsigned (&eX)[K][2][EW], unsigned (&eY)[K][2][EW])
{
    for (int p = 0; p < ITER_PAIRS; ++p) {
        int y = y0 + 2 * p;
        iter_step<0, MASK, FIRST, LAST>(y,     t, c, r0, st, f32src, bsrc, bdst, oth, a1, a2, eX, eY);
        iter_step<1, MASK, FIRST, LAST>(y + 1, t, c, r0, st, f32src, bsrc, bdst, oth, a1, a2, eX, eY);
    }
}

template<int FIRST, int LAST>
__global__ __launch_bounds__(256, 2) void skel(
    const unsigned short* __restrict__ src, unsigned short* __restrict__ dst,
    const float* __restrict__ pred32, const float* __restrict__ gt32,
    double* __restrict__ partials)
{
    __shared__ unsigned eX[K][2][EW];   // col0 pairs {x,m}
    __shared__ unsigned eY[K][2][EW];   // col3 pairs {x,m}
    __shared__ double l1[4], l2[4];

    const int t = threadIdx.x, c = 4 * t;
    const int band = blockIdx.x, z = blockIdx.y;
    const int r0 = band * BH;

    const float* f32src = (z < NIMG) ? pred32 + (size_t)z * IMG_N
                                     : gt32 + (size_t)(z - NIMG) * IMG_N;
    const unsigned short* bsrc = FIRST ? nullptr : src + (size_t)z * IMG_N;
    unsigned short* bdst = LAST ? nullptr : dst + (size_t)z * IMG_N;
    const float* oth = LAST ? ((z < NIMG) ? gt32 + (size_t)z * IMG_N
                                          : pred32 + (size_t)(z - NIMG) * IMG_N)
                            : nullptr;

    if (t < K) {
        #pragma unroll
        for (int b = 0; b < 2; ++b) {
            eY[t][b][0]      = 0xFC007C00u;  // {x=+inf, m=-inf} left guard
            eX[t][b][EW - 1] = 0xFC007C00u;  // right guard
        }
    }

    St st[K];
    #pragma unroll
    for (int k = 0; k < K; ++k) {
        st[k].hm1.lo = st[k].hm1.hi = PINF2;
        st[k].hm2.lo = st[k].hm2.hi = PINF2;
        st[k].m2.lo  = st[k].m2.hi  = NINF2;
        st[k].m3.lo  = st[k].m3.hi  = NINF2;
        st[k].q1.lo  = st[k].q1.hi  = NINF2;
        st[k].q2.lo  = st[k].q2.hi  = NINF2;
        st[k].x1.lo  = st[k].x1.hi  = PINF2;
        st[k].x2.lo  = st[k].x2.hi  = PINF2;
        st[k].x3.lo  = st[k].x3.hi  = PINF2;
        st[k].xc.lo  = st[k].xc.hi  = PINF2;
    }

    const int y0 = r0 - 2 * K;               // r0 - 10 (even: BUF parity static)
    if ((unsigned)y0 < (unsigned)IMG_H) {    // prologue load (guarded, runs once)
        if constexpr (FIRST) {
            float4 f = *(const float4*)(f32src + (size_t)y0 * IMG_W + c);
            st[0].xc.lo = (h2){(_Float16)f.x, (_Float16)f.y};
            st[0].xc.hi = (h2){(_Float16)f.z, (_Float16)f.w};
        } else {
            uint2 u = *(const uint2*)(bsrc + (size_t)y0 * IMG_W + c);
            st[0].xc.lo = as_h2(u.x); st[0].xc.hi = as_h2(u.y);
        }
    }

    // prologue edge write into buf 0 (consumed by first iteration)
    #pragma unroll
    for (int k = 0; k < K; ++k) {
        eX[k][0][t + 1] = as_u((h2){st[k].xc.lo[0], st[k].m2.lo[0]});
        eY[k][0][t + 1] = as_u((h2){st[k].xc.hi[1], st[k].m2.hi[1]});
    }

    float a1 = 0.f, a2 = 0.f;
    // interior bands never touch an image edge in any load/mask:
    //   rows used: [y0, y0+61+1] = [r0-10, r0+52] and masks need y-17 >= 0
    //   -> bands 1..30 are mask-free
    if (band >= 1 && band <= NBANDS - 2)
        run_band<false, FIRST, LAST>(y0, t, c, r0, st, f32src, bsrc, bdst, oth, a1, a2, eX, eY);
    else
        run_band<true,  FIRST, LAST>(y0, t, c, r0, st, f32src, bsrc, bdst, oth, a1, a2, eX, eY);

    if constexpr (LAST) {                    // per-block partials (no atomics)
        double d1 = a1, d2 = a2;
        for (int off = 32; off; off >>= 1) {
            d1 += __shfl_down(d1, off);
            d2 += __shfl_down(d2, off);
        }
        const int w = t >> 6;
        if ((t & 63) == 0) { l1[w] = d1; l2[w] = d2; }
        __syncthreads();
        if (t == 0) {
            int bid = z * NBANDS + band;
            partials[2 * bid]     = l1[0] + l1[1] + l1[2] + l1[3];
            partials[2 * bid + 1] = l2[0] + l2[1] + l2[2] + l2[3];
        }
    }
}

__global__ __launch_bounds__(256) void finalize(
    const double* __restrict__ pp, float* __restrict__ out)
{
    __shared__ double sh[4][4];
    double i1 = 0, i2 = 0, t1 = 0, t2 = 0;
    for (int i = threadIdx.x; i < NBLK; i += 256) {
        double a = pp[2 * i], b = pp[2 * i + 1];
        if (i < NIMG * NBANDS) { i1 += a; i2 += b; }   // z < 16: cl_pred side
        else                   { t1 += a; t2 += b; }   // z >= 16: skel_gt side
    }
    for (int off = 32; off; off >>= 1) {
        i1 += __shfl_down(i1, off); i2 += __shfl_down(i2, off);
        t1 += __shfl_down(t1, off); t2 += __shfl_down(t2, off);
    }
    const int w = threadIdx.x >> 6;
    if ((threadIdx.x & 63) == 0) { sh[0][w] = i1; sh[1][w] = i2; sh[2][w] = t1; sh[3][w] = t2; }
    __syncthreads();
    if (threadIdx.x == 0) {
        double s1 = 0, s2 = 0, s3 = 0, s4 = 0;
        for (int j = 0; j < 4; ++j) { s1 += sh[0][j]; s2 += sh[1][j]; s3 += sh[2][j]; s4 += sh[3][j]; }
        double iflat = (s1 + 1.0) / (s2 + 1.0);
        double tflat = (s3 + 1.0) / (s4 + 1.0);
        out[0] = (float)(1.0 - 2.0 * (iflat * tflat) / (iflat + tflat));
    }
}

extern "C" void kernel_launch(void* const* d_in, const int* in_sizes, int n_in,
                              void* d_out, int out_size, void* d_ws, size_t ws_size,
                              hipStream_t stream)
{
    const float* pred = (const float*)d_in[0];
    const float* gt   = (const float*)d_in[1];

    unsigned short* A = (unsigned short*)d_ws;            // 32 f16 images (64 MiB)
    unsigned short* B = A + (size_t)NZ * IMG_N;           // 32 f16 images
    double* partials  = (double*)B;                       // overlaps B; B is dead
                                                          // during launch 4 (reads A)
    dim3 grid(NBANDS, NZ);                                // 32 bands x 32 images

    skel<1, 0><<<grid, 256, 0, stream>>>(nullptr, A, pred, gt, nullptr);  // iters 1-5
    skel<0, 0><<<grid, 256, 0, stream>>>(A, B, pred, gt, nullptr);        // 6-10
    skel<0, 0><<<grid, 256, 0, stream>>>(B, A, pred, gt, nullptr);        // 11-15
    skel<0, 1><<<grid, 256, 0, stream>>>(A, nullptr, pred, gt, partials); // 16-20 + sums

    finalize<<<1, 256, 0, stream>>>(partials, (float*)d_out);
}

// Round 12
// 674.919 us; speedup vs baseline: 1.0537x; 1.0537x over previous
//
#include <hip/hip_runtime.h>
#include <math.h>

// clDice loss on MI355X (gfx950).
// soft_skeletonize = 20 iterations of:
//   m = minpool3(x); contour = relu(maxpool3(m) - m); x = relu(x - contour)
// Round-12: dual-row stage steps (R=2). Measured invariant: ~240 issue-cyc
// per stage-row at 70% duty, dominated by per-step fixed overhead (LDS edge
// ops, ring moves, barrier, addressing). Processing row PAIRS per stage-step
// pays that overhead once per 2 rows. Chaining lag 6 rows/stage (emit pair
// consumed next step); correctness frontier advances 2 rows/stage -> same
// y0 = r0-8 warm-up as the proven R10 structure. One barrier per 2 rows.
// All image-edge handling is wave-uniform: clamped row loads + scalar-selected
// +-inf mask constants folded in via pk-min/max (no divergent guards).
// Keep from R10/11: packed f16, K=4, BH=32, z=32 grid (4 blocks/CU),
// conflict-free edge exchange (dense uint2 b64, both rows packed), f16
// ping-pong intermediates, per-block partials, 5 launches + finalize.

#define IMG_H 1024
#define IMG_W 1024
#define IMG_N (IMG_H * IMG_W)
#define NIMG  16
#define NZ    32                    // 16 pred + 16 gt images
#define BH    32                    // output rows per band
#define NBANDS (IMG_H / BH)         // 32
#define K     4                     // fused skeleton iterations per launch
#define EW    258                   // 256 lanes + 2 guard slots
#define NBLK  (NZ * NBANDS)         // 1024 blocks per launch
#define NPAIR 16                    // 16 step-pairs = 32 dual-row steps

typedef _Float16 h2 __attribute__((ext_vector_type(2)));

__device__ __forceinline__ h2 hmin2(h2 a, h2 b) { return __builtin_elementwise_min(a, b); }
__device__ __forceinline__ h2 hmax2(h2 a, h2 b) { return __builtin_elementwise_max(a, b); }

union U32H { unsigned u; h2 h; };
__device__ __forceinline__ unsigned as_u(h2 h) { U32H t; t.h = h; return t.u; }
__device__ __forceinline__ h2 as_h2(unsigned u) { U32H t; t.u = u; return t.h; }

#define PXP 0x7C007C00u             // {+inf, +inf} f16 pair
#define NXP 0xFC00FC00u             // {-inf, -inf} f16 pair
#define HINF  ((_Float16)__builtin_huge_valf())
#define PINF2 ((h2){HINF, HINF})
#define NINF2 ((h2){-HINF, -HINF})

struct Hp { h2 lo, hi; };           // 4 image columns per lane

// Per-stage state at step start (stage timeline ya = y - 6k):
//  hm1 = hmin(ya-2), hm2 = hmin(ya-1)
//  mpa = m(ya-3), mpb = m(ya-2), mppb = m(ya-4)
//  qpa = q(ya-5), qpb = q(ya-4)
//  xpa = x(ya-2), xpb = x(ya-1); xppa = x(ya-4), xppb = x(ya-3)
//  xca = x(ya), xcb = x(ya+1)  (current input pair)
struct St { Hp hm1, hm2, mpa, mpb, mppb, qpa, qpb, xpa, xpb, xppa, xppb, xca, xcb; };

// One dual-row stage step: consumes input pair (ya, ya+1), emits output pair
// rows (ya-4, ya-3) into (ea, eb). LDS edges (written previous step):
//   eXk[slot] = {pack(xca.lo[0], xcb.lo[0]), pack(mpa.lo[0], mpb.lo[0])} of lane slot-1
//   eYk[slot] = {pack(xca.hi[1], xcb.hi[1]), pack(mpa.hi[1], mpb.hi[1])}
template<int BUF>
__device__ __forceinline__ void stage_step(
    St& s, int ya, int t,
    const uint2 (&eXk)[2][EW], const uint2 (&eYk)[2][EW],
    Hp& ea, Hp& eb)
{
    const h2 Z2 = (h2){(_Float16)0.f, (_Float16)0.f};
    uint2 lp = eYk[BUF][t];          // left neighbor (guard at slot 0)
    uint2 rp = eXk[BUF][t + 2];      // right neighbor (guard at slot 257)
    h2 lpx = as_h2(lp.x), lpm = as_h2(lp.y);
    h2 rpx = as_h2(rp.x), rpm = as_h2(rp.y);

    // h-min3 rows (ya, ya+1)
    h2 midA = (h2){s.xca.lo[1], s.xca.hi[0]};
    h2 haLo = hmin2(hmin2((h2){lpx[0], s.xca.lo[0]}, s.xca.lo), midA);
    h2 haHi = hmin2(hmin2(midA, s.xca.hi), (h2){s.xca.hi[1], rpx[0]});
    h2 midB = (h2){s.xcb.lo[1], s.xcb.hi[0]};
    h2 hbLo = hmin2(hmin2((h2){lpx[1], s.xcb.lo[0]}, s.xcb.lo), midB);
    h2 hbHi = hmin2(hmin2(midB, s.xcb.hi), (h2){s.xcb.hi[1], rpx[1]});

    // v-min3 -> m rows (ya-1, ya), with uniform row-validity mask
    h2 rmA = as_h2(((unsigned)(ya - 1) < (unsigned)IMG_H) ? PXP : NXP);
    h2 rmB = as_h2(((unsigned)(ya)     < (unsigned)IMG_H) ? PXP : NXP);
    h2 maLo = hmin2(hmin2(hmin2(s.hm1.lo, s.hm2.lo), haLo), rmA);
    h2 maHi = hmin2(hmin2(hmin2(s.hm1.hi, s.hm2.hi), haHi), rmA);
    h2 mbLo = hmin2(hmin2(hmin2(s.hm2.lo, haLo), hbLo), rmB);
    h2 mbHi = hmin2(hmin2(hmin2(s.hm2.hi, haHi), hbHi), rmB);

    // h-max3 -> q rows (ya-3, ya-2) on (mpa, mpb) with prev-step LDS edges
    h2 midQa = (h2){s.mpa.lo[1], s.mpa.hi[0]};
    h2 qaLo = hmax2(hmax2((h2){lpm[0], s.mpa.lo[0]}, s.mpa.lo), midQa);
    h2 qaHi = hmax2(hmax2(midQa, s.mpa.hi), (h2){s.mpa.hi[1], rpm[0]});
    h2 midQb = (h2){s.mpb.lo[1], s.mpb.hi[0]};
    h2 qbLo = hmax2(hmax2((h2){lpm[1], s.mpb.lo[0]}, s.mpb.lo), midQb);
    h2 qbHi = hmax2(hmax2(midQb, s.mpb.hi), (h2){s.mpb.hi[1], rpm[1]});

    // v-max3 -> M rows (ya-4, ya-3)
    h2 MaLo = hmax2(hmax2(s.qpa.lo, s.qpb.lo), qaLo);
    h2 MaHi = hmax2(hmax2(s.qpa.hi, s.qpb.hi), qaHi);
    h2 MbLo = hmax2(hmax2(s.qpb.lo, qaLo), qbLo);
    h2 MbHi = hmax2(hmax2(s.qpb.hi, qaHi), qbHi);

    // out rows (ya-4, ya-3): x from xpp pair; m(ya-4)=mppb, m(ya-3)=mpa
    ea.lo = hmax2(s.xppa.lo - hmax2(MaLo - s.mppb.lo, Z2), Z2);
    ea.hi = hmax2(s.xppa.hi - hmax2(MaHi - s.mppb.hi, Z2), Z2);
    eb.lo = hmax2(s.xppb.lo - hmax2(MbLo - s.mpa.lo, Z2), Z2);
    eb.hi = hmax2(s.xppb.hi - hmax2(MbHi - s.mpa.hi, Z2), Z2);

    // ring shifts (pair-replacing; unroll-by-2 renames most)
    s.hm1.lo = haLo; s.hm1.hi = haHi; s.hm2.lo = hbLo; s.hm2.hi = hbHi;
    s.mppb = s.mpb;
    s.mpa.lo = maLo; s.mpa.hi = maHi; s.mpb.lo = mbLo; s.mpb.hi = mbHi;
    s.qpa.lo = qaLo; s.qpa.hi = qaHi; s.qpb.lo = qbLo; s.qpb.hi = qbHi;
    s.xppa = s.xpa; s.xppb = s.xpb; s.xpa = s.xca; s.xpb = s.xcb;
    // xca/xcb overwritten by caller (chain or load)
}

template<int BUF, int FIRST, int LAST>
__device__ __forceinline__ void iter_step(
    int y, int t, int c, int r0, St (&st)[K],
    const float* __restrict__ f32src, const unsigned short* __restrict__ bsrc,
    unsigned short* __restrict__ bdst, const float* __restrict__ oth,
    float& a1, float& a2,
    uint2 (&eX)[K][2][EW], uint2 (&eY)[K][2][EW])
{
    // ---- load next stage-0 input pair: rows (y+2, y+3), clamped + masked ----
    int la = y + 2; la = la < 0 ? 0 : (la > IMG_H - 1 ? IMG_H - 1 : la);
    int lb = y + 3; lb = lb < 0 ? 0 : (lb > IMG_H - 1 ? IMG_H - 1 : lb);
    h2 gA = as_h2(((unsigned)(y + 2) < (unsigned)IMG_H) ? NXP : PXP);
    h2 gB = as_h2(((unsigned)(y + 3) < (unsigned)IMG_H) ? NXP : PXP);
    Hp xna, xnb;
    if constexpr (FIRST) {
        float4 fa = *(const float4*)(f32src + (size_t)la * IMG_W + c);
        float4 fb = *(const float4*)(f32src + (size_t)lb * IMG_W + c);
        xna.lo = (h2){(_Float16)fa.x, (_Float16)fa.y};
        xna.hi = (h2){(_Float16)fa.z, (_Float16)fa.w};
        xnb.lo = (h2){(_Float16)fb.x, (_Float16)fb.y};
        xnb.hi = (h2){(_Float16)fb.z, (_Float16)fb.w};
    } else {
        uint2 ua = *(const uint2*)(bsrc + (size_t)la * IMG_W + c);
        uint2 ub = *(const uint2*)(bsrc + (size_t)lb * IMG_W + c);
        xna.lo = as_h2(ua.x); xna.hi = as_h2(ua.y);
        xnb.lo = as_h2(ub.x); xnb.hi = as_h2(ub.y);
    }
    xna.lo = hmax2(xna.lo, gA); xna.hi = hmax2(xna.hi, gA);
    xnb.lo = hmax2(xnb.lo, gB); xnb.hi = hmax2(xnb.hi, gB);

    __syncthreads();                 // prev-step edge writes visible

    // ---- stage K-1 first (outputs), then reverse chain ----
    Hp ea, eb;
    stage_step<BUF>(st[K - 1], y - 6 * (K - 1), t, eX[K - 1], eY[K - 1], ea, eb);
    int orow = y - 6 * (K - 1) - 4;  // y - 22
    if ((unsigned)(orow - r0) < (unsigned)BH) {
        if constexpr (!LAST) {
            *(uint2*)(bdst + (size_t)orow * IMG_W + c) = make_uint2(as_u(ea.lo), as_u(ea.hi));
        } else {
            float4 ov = *(const float4*)(oth + (size_t)orow * IMG_W + c);
            float e0 = (float)ea.lo[0], e1 = (float)ea.lo[1];
            float e2 = (float)ea.hi[0], e3 = (float)ea.hi[1];
            a1 += e0 * ov.x + e1 * ov.y + e2 * ov.z + e3 * ov.w;
            a2 += e0 + e1 + e2 + e3;
        }
    }
    if ((unsigned)(orow + 1 - r0) < (unsigned)BH) {
        if constexpr (!LAST) {
            *(uint2*)(bdst + (size_t)(orow + 1) * IMG_W + c) = make_uint2(as_u(eb.lo), as_u(eb.hi));
        } else {
            float4 ov = *(const float4*)(oth + (size_t)(orow + 1) * IMG_W + c);
            float e0 = (float)eb.lo[0], e1 = (float)eb.lo[1];
            float e2 = (float)eb.hi[0], e3 = (float)eb.hi[1];
            a1 += e0 * ov.x + e1 * ov.y + e2 * ov.z + e3 * ov.w;
            a2 += e0 + e1 + e2 + e3;
        }
    }

    #pragma unroll
    for (int k = K - 2; k >= 0; --k) {
        Hp fa, fb;
        int ya = y - 6 * k;
        stage_step<BUF>(st[k], ya, t, eX[k], eY[k], fa, fb);
        // emit pair rows (ya-4, ya-3) -> next stage's input pair next step
        h2 eA = as_h2(((unsigned)(ya - 4) < (unsigned)IMG_H) ? NXP : PXP);
        h2 eB = as_h2(((unsigned)(ya - 3) < (unsigned)IMG_H) ? NXP : PXP);
        st[k + 1].xca.lo = hmax2(fa.lo, eA); st[k + 1].xca.hi = hmax2(fa.hi, eA);
        st[k + 1].xcb.lo = hmax2(fb.lo, eB); st[k + 1].xcb.hi = hmax2(fb.hi, eB);
    }
    st[0].xca = xna; st[0].xcb = xnb;

    // ---- edge writes for next step (new xc pair + new m pair) ----
    #pragma unroll
    for (int k = 0; k < K; ++k) {
        eX[k][BUF ^ 1][t + 1] = make_uint2(
            as_u((h2){st[k].xca.lo[0], st[k].xcb.lo[0]}),
            as_u((h2){st[k].mpa.lo[0], st[k].mpb.lo[0]}));
        eY[k][BUF ^ 1][t + 1] = make_uint2(
            as_u((h2){st[k].xca.hi[1], st[k].xcb.hi[1]}),
            as_u((h2){st[k].mpa.hi[1], st[k].mpb.hi[1]}));
    }
}

template<int FIRST, int LAST>
__global__ __launch_bounds__(256, 2) void skel(
    const unsigned short* __restrict__ src, unsigned short* __restrict__ dst,
    const float* __restrict__ pred32, const float* __restrict__ gt32,
    double* __restrict__ partials)
{
    __shared__ uint2 eX[K][2][EW];   // col0-side packs {x rows a|b, m rows a|b}
    __shared__ uint2 eY[K][2][EW];   // col3-side packs
    __shared__ double l1[4], l2[4];

    const int t = threadIdx.x, c = 4 * t;
    const int band = blockIdx.x, z = blockIdx.y;
    const int r0 = band * BH;

    const float* f32src = (z < NIMG) ? pred32 + (size_t)z * IMG_N
                                     : gt32 + (size_t)(z - NIMG) * IMG_N;
    const unsigned short* bsrc = FIRST ? nullptr : src + (size_t)z * IMG_N;
    unsigned short* bdst = LAST ? nullptr : dst + (size_t)z * IMG_N;
    const float* oth = LAST ? ((z < NIMG) ? gt32 + (size_t)z * IMG_N
                                          : pred32 + (size_t)(z - NIMG) * IMG_N)
                            : nullptr;

    if (t < K) {
        #pragma unroll
        for (int b = 0; b < 2; ++b) {
            eY[t][b][0]      = make_uint2(PXP, NXP);  // image-left guard
            eX[t][b][EW - 1] = make_uint2(PXP, NXP);  // image-right guard
        }
    }

    St st[K];
    #pragma unroll
    for (int k = 0; k < K; ++k) {
        st[k].hm1.lo = st[k].hm1.hi = PINF2;
        st[k].hm2.lo = st[k].hm2.hi = PINF2;
        st[k].mpa.lo = st[k].mpa.hi = NINF2;
        st[k].mpb.lo = st[k].mpb.hi = NINF2;
        st[k].mppb.lo = st[k].mppb.hi = NINF2;
        st[k].qpa.lo = st[k].qpa.hi = NINF2;
        st[k].qpb.lo = st[k].qpb.hi = NINF2;
        st[k].xpa.lo = st[k].xpa.hi = PINF2;
        st[k].xpb.lo = st[k].xpb.hi = PINF2;
        st[k].xppa.lo = st[k].xppa.hi = PINF2;
        st[k].xppb.lo = st[k].xppb.hi = PINF2;
        st[k].xca.lo = st[k].xca.hi = PINF2;
        st[k].xcb.lo = st[k].xcb.hi = PINF2;
    }

    // stage-0 initial input pair: rows (y0, y0+1), clamped + masked
    const int y0 = r0 - 8;
    {
        int la = y0 < 0 ? 0 : y0;
        int lb = y0 + 1 < 0 ? 0 : y0 + 1;
        h2 gA = as_h2(((unsigned)y0 < (unsigned)IMG_H) ? NXP : PXP);
        h2 gB = as_h2(((unsigned)(y0 + 1) < (unsigned)IMG_H) ? NXP : PXP);
        if constexpr (FIRST) {
            float4 fa = *(const float4*)(f32src + (size_t)la * IMG_W + c);
            float4 fb = *(const float4*)(f32src + (size_t)lb * IMG_W + c);
            st[0].xca.lo = hmax2((h2){(_Float16)fa.x, (_Float16)fa.y}, gA);
            st[0].xca.hi = hmax2((h2){(_Float16)fa.z, (_Float16)fa.w}, gA);
            st[0].xcb.lo = hmax2((h2){(_Float16)fb.x, (_Float16)fb.y}, gB);
            st[0].xcb.hi = hmax2((h2){(_Float16)fb.z, (_Float16)fb.w}, gB);
        } else {
            uint2 ua = *(const uint2*)(bsrc + (size_t)la * IMG_W + c);
            uint2 ub = *(const uint2*)(bsrc + (size_t)lb * IMG_W + c);
            st[0].xca.lo = hmax2(as_h2(ua.x), gA);
            st[0].xca.hi = hmax2(as_h2(ua.y), gA);
            st[0].xcb.lo = hmax2(as_h2(ub.x), gB);
            st[0].xcb.hi = hmax2(as_h2(ub.y), gB);
        }
    }

    // prologue edge write into buf 0
    #pragma unroll
    for (int k = 0; k < K; ++k) {
        eX[k][0][t + 1] = make_uint2(
            as_u((h2){st[k].xca.lo[0], st[k].xcb.lo[0]}),
            as_u((h2){st[k].mpa.lo[0], st[k].mpb.lo[0]}));
        eY[k][0][t + 1] = make_uint2(
            as_u((h2){st[k].xca.hi[1], st[k].xcb.hi[1]}),
            as_u((h2){st[k].mpa.hi[1], st[k].mpb.hi[1]}));
    }

    float a1 = 0.f, a2 = 0.f;
    for (int p = 0; p < NPAIR; ++p) {
        int y = y0 + 4 * p;
        iter_step<0, FIRST, LAST>(y,     t, c, r0, st, f32src, bsrc, bdst, oth, a1, a2, eX, eY);
        iter_step<1, FIRST, LAST>(y + 2, t, c, r0, st, f32src, bsrc, bdst, oth, a1, a2, eX, eY);
    }

    if constexpr (LAST) {                    // per-block partials (no atomics)
        double d1 = a1, d2 = a2;
        for (int off = 32; off; off >>= 1) {
            d1 += __shfl_down(d1, off);
            d2 += __shfl_down(d2, off);
        }
        const int w = t >> 6;
        if ((t & 63) == 0) { l1[w] = d1; l2[w] = d2; }
        __syncthreads();
        if (t == 0) {
            int bid = z * NBANDS + band;
            partials[2 * bid]     = l1[0] + l1[1] + l1[2] + l1[3];
            partials[2 * bid + 1] = l2[0] + l2[1] + l2[2] + l2[3];
        }
    }
}

__global__ __launch_bounds__(256) void finalize(
    const double* __restrict__ pp, float* __restrict__ out)
{
    __shared__ double sh[4][4];
    double i1 = 0, i2 = 0, t1 = 0, t2 = 0;
    for (int i = threadIdx.x; i < NBLK; i += 256) {
        double a = pp[2 * i], b = pp[2 * i + 1];
        if (i < NIMG * NBANDS) { i1 += a; i2 += b; }   // z < 16: cl_pred side
        else                   { t1 += a; t2 += b; }   // z >= 16: skel_gt side
    }
    for (int off = 32; off; off >>= 1) {
        i1 += __shfl_down(i1, off); i2 += __shfl_down(i2, off);
        t1 += __shfl_down(t1, off); t2 += __shfl_down(t2, off);
    }
    const int w = threadIdx.x >> 6;
    if ((threadIdx.x & 63) == 0) { sh[0][w] = i1; sh[1][w] = i2; sh[2][w] = t1; sh[3][w] = t2; }
    __syncthreads();
    if (threadIdx.x == 0) {
        double s1 = 0, s2 = 0, s3 = 0, s4 = 0;
        for (int j = 0; j < 4; ++j) { s1 += sh[0][j]; s2 += sh[1][j]; s3 += sh[2][j]; s4 += sh[3][j]; }
        double iflat = (s1 + 1.0) / (s2 + 1.0);
        double tflat = (s3 + 1.0) / (s4 + 1.0);
        out[0] = (float)(1.0 - 2.0 * (iflat * tflat) / (iflat + tflat));
    }
}

extern "C" void kernel_launch(void* const* d_in, const int* in_sizes, int n_in,
                              void* d_out, int out_size, void* d_ws, size_t ws_size,
                              hipStream_t stream)
{
    const float* pred = (const float*)d_in[0];
    const float* gt   = (const float*)d_in[1];

    unsigned short* A = (unsigned short*)d_ws;            // 32 f16 images (64 MiB)
    unsigned short* B = A + (size_t)NZ * IMG_N;           // 32 f16 images
    double* partials  = (double*)d_ws;                    // overlaps A; A is dead
                                                          // during launch 5 (reads B)
    dim3 grid(NBANDS, NZ);                                // 32 bands x 32 images

    skel<1, 0><<<grid, 256, 0, stream>>>(nullptr, A, pred, gt, nullptr);  // iters 1-4
    skel<0, 0><<<grid, 256, 0, stream>>>(A, B, pred, gt, nullptr);        // 5-8
    skel<0, 0><<<grid, 256, 0, stream>>>(B, A, pred, gt, nullptr);        // 9-12
    skel<0, 0><<<grid, 256, 0, stream>>>(A, B, pred, gt, nullptr);        // 13-16
    skel<0, 1><<<grid, 256, 0, stream>>>(B, nullptr, pred, gt, partials); // 17-20 + sums

    finalize<<<1, 256, 0, stream>>>(partials, (float*)d_out);
}